// Round 8
// baseline (526.277 us; speedup 1.0000x reference)
//
#include <hip/hip_runtime.h>
#include <cstdint>
#include <cstddef>

#define LEAKY_SLOPE 0.2f

typedef __attribute__((ext_vector_type(8))) short short8;   // 8 x bf16 frag
typedef __attribute__((ext_vector_type(4))) float f32x4;
typedef __attribute__((ext_vector_type(2))) float f32x2;

// ---- bf16 helpers (manual; RNE; inputs finite) ----
static __device__ inline unsigned short f2b(float f) {
  union { float f; unsigned int u; } c; c.f = f;
  unsigned int u = c.u;
  unsigned int r = (u + 0x7fffu + ((u >> 16) & 1u)) >> 16;
  return (unsigned short)r;
}
static __device__ inline float b2f(unsigned short b) {
  union { unsigned int u; float f; } c; c.u = ((unsigned int)b) << 16;
  return c.f;
}
// fp8 e4m3 (self-consistent encode/decode via HW cvt)
static __device__ inline unsigned char f2f8(float v) {
  int pk = __builtin_amdgcn_cvt_pk_fp8_f32(v, v, 0, false);
  return (unsigned char)(pk & 0xff);
}

// ================================================================ CSR build
__global__ __launch_bounds__(256) void k_bhist(const int* __restrict__ dst,
                                               int* __restrict__ gcount,
                                               int E, int N, int NB) {
  __shared__ int lh[512];
  for (int i = threadIdx.x; i < NB; i += 256) lh[i] = 0;
  __syncthreads();
  int stride = gridDim.x * blockDim.x;
  for (int idx = blockIdx.x * blockDim.x + threadIdx.x; idx < E + N; idx += stride) {
    int d = (idx < E) ? dst[idx] : (idx - E);   // self-loops at tail
    atomicAdd(&lh[d >> 8], 1);
  }
  __syncthreads();
  for (int i = threadIdx.x; i < NB; i += 256)
    if (lh[i]) atomicAdd(&gcount[i], lh[i]);
}

__global__ __launch_bounds__(512) void k_bscan(const int* __restrict__ gcount,
                                               int* __restrict__ gbase,
                                               int* __restrict__ gcursor,
                                               int NB, int ET, int* __restrict__ offN) {
  __shared__ int sm[512];
  int t = threadIdx.x;
  int v = (t < NB) ? gcount[t] : 0;
  sm[t] = v;
  __syncthreads();
  for (int o = 1; o < 512; o <<= 1) {
    int x = (t >= o) ? sm[t - o] : 0;
    __syncthreads();
    sm[t] += x;
    __syncthreads();
  }
  if (t < NB) {
    int b = sm[t] - v;
    gbase[t] = b;
    gcursor[t] = b;
  }
  if (t == 0) { gbase[NB] = ET; *offN = ET; }
}

template <int CHUNK>
__global__ __launch_bounds__(256) void k_binpass(const int* __restrict__ src,
                                                 const int* __restrict__ dst,
                                                 int* __restrict__ gcursor,
                                                 unsigned int* __restrict__ staging,
                                                 int E, int N, int NB) {
  __shared__ int lh[512];
  __shared__ int lbase[512];
  const int t = threadIdx.x;
  const int ET = E + N;
  const int e0 = blockIdx.x * CHUNK;
  const int e1 = min(e0 + CHUNK, ET);
  for (int i = t; i < NB; i += 256) lh[i] = 0;
  __syncthreads();
  for (int i = e0 + t; i < e1; i += 256) {
    int d = (i < E) ? dst[i] : (i - E);
    atomicAdd(&lh[d >> 8], 1);
  }
  __syncthreads();
  for (int i = t; i < NB; i += 256) {
    int c = lh[i];
    lbase[i] = c ? atomicAdd(&gcursor[i], c) : 0;
    lh[i] = 0;                       // reuse as local cursor
  }
  __syncthreads();
  for (int i = e0 + t; i < e1; i += 256) {
    int s, d;
    if (i < E) { s = src[i]; d = dst[i]; }
    else       { s = d = i - E; }
    int b = d >> 8;
    int r = atomicAdd(&lh[b], 1);
    staging[lbase[b] + r] = ((unsigned int)s << 8) | (unsigned int)(d & 255);
  }
}

__global__ __launch_bounds__(256) void k_csrbuild(const int* __restrict__ gbase,
                                                  const unsigned int* __restrict__ staging,
                                                  int* __restrict__ off,
                                                  int* __restrict__ csr,
                                                  int N) {
  __shared__ int sc[256];
  __shared__ int cur[256];
  const int b = blockIdx.x, t = threadIdx.x;
  const int s0 = gbase[b], s1 = gbase[b + 1];
  cur[t] = 0;
  __syncthreads();
  for (int i = s0 + t; i < s1; i += 256)
    atomicAdd(&cur[staging[i] & 255], 1);
  __syncthreads();
  int v = cur[t];
  sc[t] = v;
  __syncthreads();
  for (int o = 1; o < 256; o <<= 1) {
    int x = (t >= o) ? sc[t - o] : 0;
    __syncthreads();
    sc[t] += x;
    __syncthreads();
  }
  int excl = s0 + sc[t] - v;
  int node = b * 256 + t;
  if (node < N) off[node] = excl;
  __syncthreads();
  cur[t] = excl;
  __syncthreads();
  for (int i = s0 + t; i < s1; i += 256) {
    unsigned int pv = staging[i];
    int slot = atomicAdd(&cur[pv & 255], 1);
    csr[slot] = (int)(pv >> 8);
  }
}

// ---------------------------------------------------------------- weights prep
// W1t = W1^T bf16; va_s = W2 @ a2_src, va_d = W2 @ a2_dst (f32, 128-dim).
__global__ __launch_bounds__(256) void k_prep_w(const float* __restrict__ W1,
                                                const float* __restrict__ W2,
                                                const float* __restrict__ a2_src,
                                                const float* __restrict__ a2_dst,
                                                unsigned short* __restrict__ W1t,
                                                float* __restrict__ va_s,
                                                float* __restrict__ va_d) {
  int t = threadIdx.x;
  for (int o = t; o < 128 * 128; o += 256) {
    int n = o >> 7, k = o & 127;
    W1t[o] = f2b(W1[k * 128 + n]);
  }
  if (t < 128) {
    float s = 0.f, d = 0.f;
    for (int c = 0; c < 64; ++c) {
      float w = W2[t * 64 + c];
      s += w * a2_src[c];
      d += w * a2_dst[c];
    }
    va_s[t] = s;
    va_d[t] = d;
  }
}

// ---------------------------------------------------------------- MFMA GEMM (layer 1)
// h1 = x @ W1 (bf16 MFMA), stored fp8; fused alpha1 epilogue on f32 acc.
__global__ __launch_bounds__(256) void k_gemm1(const float* __restrict__ Ap,
                                               const unsigned short* __restrict__ Bt,
                                               unsigned char* __restrict__ C,
                                               const float* __restrict__ av_src,
                                               const float* __restrict__ av_dst,
                                               float* __restrict__ as_,
                                               float* __restrict__ ad_,
                                               int N) {
  constexpr int K = 128, COLS = 128;
  constexpr int LDA = K + 8;
  __shared__ __align__(16) unsigned short As[64 * LDA];
  __shared__ __align__(16) unsigned short Bs[COLS * LDA];
  const int t = threadIdx.x;
  const int wave = t >> 6, lane = t & 63;
  const int row0 = blockIdx.x * 64;

#pragma unroll
  for (int i = 0; i < 4; ++i) {
    int c = t + 256 * i;
    int r = c >> 4, cq = c & 15;
    int4 v = make_int4(0, 0, 0, 0);
    if (row0 + r < N) {
      const float* Ar = Ap + (size_t)(row0 + r) * K + cq * 8;
      float4 u = *reinterpret_cast<const float4*>(Ar);
      float4 w = *reinterpret_cast<const float4*>(Ar + 4);
      v.x = (int)f2b(u.x) | ((int)f2b(u.y) << 16);
      v.y = (int)f2b(u.z) | ((int)f2b(u.w) << 16);
      v.z = (int)f2b(w.x) | ((int)f2b(w.y) << 16);
      v.w = (int)f2b(w.z) | ((int)f2b(w.w) << 16);
    }
    *reinterpret_cast<int4*>(&As[r * LDA + cq * 8]) = v;
  }
#pragma unroll
  for (int i = 0; i < COLS / 16; ++i) {
    int c = t + 256 * i;
    int r = c >> 4, cq = c & 15;
    *reinterpret_cast<int4*>(&Bs[r * LDA + cq * 8]) =
        *reinterpret_cast<const int4*>(Bt + (size_t)r * K + cq * 8);
  }
  __syncthreads();

  const int m15 = lane & 15;
  const int koff = (lane >> 4) * 8;
  const int arow = wave * 16 + m15;

  f32x4 acc[COLS / 16];
#pragma unroll
  for (int ct = 0; ct < COLS / 16; ++ct) acc[ct] = (f32x4){0.f, 0.f, 0.f, 0.f};

#pragma unroll
  for (int kk = 0; kk < K / 32; ++kk) {
    short8 af = *reinterpret_cast<const short8*>(&As[arow * LDA + kk * 32 + koff]);
#pragma unroll
    for (int ct = 0; ct < COLS / 16; ++ct) {
      short8 bf = *reinterpret_cast<const short8*>(&Bs[(ct * 16 + m15) * LDA + kk * 32 + koff]);
      acc[ct] = __builtin_amdgcn_mfma_f32_16x16x32_bf16(af, bf, acc[ct], 0, 0, 0);
    }
  }

  // C store (fp8 bytes)
#pragma unroll
  for (int ct = 0; ct < COLS / 16; ++ct) {
#pragma unroll
    for (int r = 0; r < 4; ++r) {
      int grow = row0 + wave * 16 + (lane >> 4) * 4 + r;
      if (grow < N)
        C[(size_t)grow * COLS + ct * 16 + m15] = f2f8(acc[ct][r]);
    }
  }

  // fused alpha epilogue (f32-accurate)
  {
    float ps[4] = {0.f, 0.f, 0.f, 0.f}, pd[4] = {0.f, 0.f, 0.f, 0.f};
#pragma unroll
    for (int ct = 0; ct < COLS / 16; ++ct) {
      float av = av_src[ct * 16 + m15];
      float bv = av_dst[ct * 16 + m15];
#pragma unroll
      for (int r = 0; r < 4; ++r) {
        ps[r] += acc[ct][r] * av;
        pd[r] += acc[ct][r] * bv;
      }
    }
#pragma unroll
    for (int o = 1; o < 16; o <<= 1) {
#pragma unroll
      for (int r = 0; r < 4; ++r) {
        ps[r] += __shfl_xor(ps[r], o);
        pd[r] += __shfl_xor(pd[r], o);
      }
    }
    if (m15 == 0) {
#pragma unroll
      for (int r = 0; r < 4; ++r) {
        int grow = row0 + wave * 16 + (lane >> 4) * 4 + r;
        if (grow < N) { as_[grow] = ps[r]; ad_[grow] = pd[r]; }
      }
    }
  }
}

// ---------------------------------------------------------------- layer-1 aggregation
// One wave per dst node, single pass over fp8 h1 (F=128):
//   g1 = relu((sum_j exp(e_j) h[src_j]) / sum_j exp(e_j) + b1)
// Epilogue also emits as2 = g1.va_s, ad2 = g1.va_d (layer-2 attention halves).
template <int DEPTH>
__global__ __launch_bounds__(256) void k_agg1(const int* __restrict__ off,
                                              const int* __restrict__ csr,
                                              const float* __restrict__ as_,
                                              const float* __restrict__ ad_,
                                              const unsigned char* __restrict__ h,
                                              const float* __restrict__ bias,
                                              const float* __restrict__ va_s,
                                              const float* __restrict__ va_d,
                                              unsigned short* __restrict__ g1,
                                              float* __restrict__ as2,
                                              float* __restrict__ ad2,
                                              int N) {
  constexpr int F = 128, LPR = 16, GPI = 4;   // lanes/row, rows per wave-load
  int wid = (blockIdx.x * blockDim.x + threadIdx.x) >> 6;
  int lane = threadIdx.x & 63;
  if (wid >= N) return;
  const int s0 = off[wid], s1 = off[wid + 1];
  const float adv = ad_[wid];
  const int g  = lane / LPR;
  const int fl = lane % LPR;
  const unsigned char* hb = h + (size_t)fl * 8;

  f32x2 acc2[4] = {{0.f, 0.f}, {0.f, 0.f}, {0.f, 0.f}, {0.f, 0.f}};
  float lsum = 0.f;

  for (int base = s0; base < s1; base += 64) {
    int i = base + lane;
    int sv = 0;
    float wexp = 0.f;
    if (i < s1) {
      sv = csr[i];
      float e = as_[sv] + adv;
      e = (e > 0.f) ? e : LEAKY_SLOPE * e;
      wexp = __expf(e);
      lsum += wexp;
    }
    const int jn = min(64, s1 - base);
    int jj = 0;
    for (; jj + DEPTH * GPI <= jn; jj += DEPTH * GPI) {
      int sj[DEPTH];
      float wv[DEPTH];
      uint2 u[DEPTH];
#pragma unroll
      for (int k = 0; k < DEPTH; ++k) {
        sj[k] = __shfl(sv, jj + g + k * GPI);
        wv[k] = __shfl(wexp, jj + g + k * GPI);
      }
#pragma unroll
      for (int k = 0; k < DEPTH; ++k)
        u[k] = *reinterpret_cast<const uint2*>(hb + (size_t)sj[k] * F);
#pragma unroll
      for (int k = 0; k < DEPTH; ++k) {
        f32x2 w2 = {wv[k], wv[k]};
        acc2[0] += w2 * __builtin_amdgcn_cvt_pk_f32_fp8(u[k].x, false);
        acc2[1] += w2 * __builtin_amdgcn_cvt_pk_f32_fp8(u[k].x, true);
        acc2[2] += w2 * __builtin_amdgcn_cvt_pk_f32_fp8(u[k].y, false);
        acc2[3] += w2 * __builtin_amdgcn_cvt_pk_f32_fp8(u[k].y, true);
      }
    }
    for (; jj < jn; jj += GPI) {
      int sj0 = __shfl(sv, jj + g);        // <= 63 always; zero-weight slack ok
      float w0 = __shfl(wexp, jj + g);
      uint2 u0 = *reinterpret_cast<const uint2*>(hb + (size_t)sj0 * F);
      f32x2 w2 = {w0, w0};
      acc2[0] += w2 * __builtin_amdgcn_cvt_pk_f32_fp8(u0.x, false);
      acc2[1] += w2 * __builtin_amdgcn_cvt_pk_f32_fp8(u0.x, true);
      acc2[2] += w2 * __builtin_amdgcn_cvt_pk_f32_fp8(u0.y, false);
      acc2[3] += w2 * __builtin_amdgcn_cvt_pk_f32_fp8(u0.y, true);
    }
  }

  // denominator
  for (int o = 32; o; o >>= 1) lsum += __shfl_xor(lsum, o);
  const float inv_s = 1.f / (lsum + 1e-16f);

  // cross-group feature reduction
#pragma unroll
  for (int o = LPR; o < 64; o <<= 1) {
#pragma unroll
    for (int k = 0; k < 4; ++k) {
      acc2[k][0] += __shfl_xor(acc2[k][0], o);
      acc2[k][1] += __shfl_xor(acc2[k][1], o);
    }
  }

  if (g == 0) {
    float ov[8];
#pragma unroll
    for (int k = 0; k < 8; ++k) {
      ov[k] = fmaxf(acc2[k >> 1][k & 1] * inv_s + bias[fl * 8 + k], 0.f);
    }
    int4 pk;
    pk.x = (int)f2b(ov[0]) | ((int)f2b(ov[1]) << 16);
    pk.y = (int)f2b(ov[2]) | ((int)f2b(ov[3]) << 16);
    pk.z = (int)f2b(ov[4]) | ((int)f2b(ov[5]) << 16);
    pk.w = (int)f2b(ov[6]) | ((int)f2b(ov[7]) << 16);
    *reinterpret_cast<int4*>(g1 + (size_t)wid * F + fl * 8) = pk;

    // layer-2 attention halves: as2 = g1_row . va_s, ad2 = g1_row . va_d
    float ps = 0.f, pd = 0.f;
#pragma unroll
    for (int k = 0; k < 8; ++k) {
      ps += ov[k] * va_s[fl * 8 + k];
      pd += ov[k] * va_d[fl * 8 + k];
    }
#pragma unroll
    for (int o = 1; o < 16; o <<= 1) {
      ps += __shfl_xor(ps, o);
      pd += __shfl_xor(pd, o);
    }
    if (lane == 0) { as2[wid] = ps; ad2[wid] = pd; }
  }
}

// ---------------------------------------------------------------- layer-2 coefficients
// Per dst node d: S_d = sum exp(e); scatter c_e = exp(e)/S_d onto src via an
// 8-way REPLICATED accumulator (replica = blockIdx&7) so each replica's lines
// stay owned by ~one XCD -- no cross-XCD line ping-pong (R7 post-mortem).
__global__ __launch_bounds__(256) void k_coef(const int* __restrict__ off,
                                              const int* __restrict__ csr,
                                              const float* __restrict__ as2,
                                              const float* __restrict__ ad2,
                                              float* __restrict__ C8, int N) {
  int wid = (blockIdx.x * blockDim.x + threadIdx.x) >> 6;
  int lane = threadIdx.x & 63;
  if (wid >= N) return;
  const int s0 = off[wid], s1 = off[wid + 1];
  const float adv = ad2[wid];
  float* __restrict__ C = C8 + (size_t)(blockIdx.x & 7) * N;

  float lsum = 0.f;
  for (int base = s0; base < s1; base += 64) {
    int i = base + lane;
    if (i < s1) {
      float e = as2[csr[i]] + adv;
      e = (e > 0.f) ? e : LEAKY_SLOPE * e;
      lsum += __expf(e);
    }
  }
  for (int o = 32; o; o >>= 1) lsum += __shfl_xor(lsum, o);
  const float inv_s = 1.f / (lsum + 1e-16f);

  for (int base = s0; base < s1; base += 64) {
    int i = base + lane;
    if (i < s1) {
      int sv = csr[i];
      float e = as2[sv] + adv;
      e = (e > 0.f) ? e : LEAKY_SLOPE * e;
      atomicAdd(&C[sv], __expf(e) * inv_s);
    }
  }
}

// ---------------------------------------------------------------- weighted row-sum
// v[f] = sum_s (sum_r C8[r][s]) * g1[s][f]   (128-dim)
__global__ __launch_bounds__(256) void k_wsum(const unsigned short* __restrict__ g1,
                                              const float* __restrict__ C8,
                                              float* __restrict__ v, int N) {
  __shared__ float sm[256];
  const int f = threadIdx.x & 127, half = threadIdx.x >> 7;
  float acc = 0.f;
  for (int r = blockIdx.x * 2 + half; r < N; r += gridDim.x * 2) {
    float cs = 0.f;
#pragma unroll
    for (int k = 0; k < 8; ++k) cs += C8[(size_t)k * N + r];
    acc += cs * b2f(g1[(size_t)r * 128 + f]);
  }
  sm[threadIdx.x] = acc;
  __syncthreads();
  if (half == 0) atomicAdd(&v[f], sm[threadIdx.x] + sm[threadIdx.x + 128]);
}

// ---------------------------------------------------------------- finish
// out[c] = (sum_k v[k] W2[k][c]) / N + b2[c]
__global__ __launch_bounds__(64) void k_finish(const float* __restrict__ v,
                                               const float* __restrict__ W2,
                                               const float* __restrict__ b2,
                                               float* __restrict__ out, float invN) {
  int c = threadIdx.x;
  float s = 0.f;
  for (int k = 0; k < 128; ++k) s += v[k] * W2[k * 64 + c];
  out[c] = s * invN + b2[c];
}

// ---------------------------------------------------------------- launch
extern "C" void kernel_launch(void* const* d_in, const int* in_sizes, int n_in,
                              void* d_out, int out_size, void* d_ws, size_t ws_size,
                              hipStream_t stream) {
  (void)n_in; (void)out_size; (void)ws_size;
  const float* x      = (const float*)d_in[0];
  const int*   edges  = (const int*)d_in[1];
  const float* W1     = (const float*)d_in[2];
  const float* a1_src = (const float*)d_in[3];
  const float* a1_dst = (const float*)d_in[4];
  const float* b1     = (const float*)d_in[5];
  const float* W2     = (const float*)d_in[6];
  const float* a2_src = (const float*)d_in[7];
  const float* a2_dst = (const float*)d_in[8];
  const float* b2     = (const float*)d_in[9];
  float* out = (float*)d_out;

  const int N = in_sizes[0] / 128;     // 100000
  const int E = in_sizes[1] / 2;       // 3200000
  const int ET = E + N;
  const int NB = (N + 255) >> 8;       // 391 buckets of 256 nodes

  const int* e_src = edges;
  const int* e_dst = edges + E;

  char* ws = (char*)d_ws;
  size_t o = 0;
  auto alloc = [&](size_t bytes) {
    size_t p = o;
    o += (bytes + 511) & ~(size_t)511;
    return p;
  };
  unsigned char*  h1f = (unsigned char*)(ws + alloc((size_t)N * 128));
  unsigned short* g1b = (unsigned short*)(ws + alloc((size_t)N * 128 * 2));
  float* as1    = (float*)(ws + alloc((size_t)N * 4));
  float* ad1    = (float*)(ws + alloc((size_t)N * 4));
  float* as2    = (float*)(ws + alloc((size_t)N * 4));
  float* ad2    = (float*)(ws + alloc((size_t)N * 4));
  float* Cv8    = (float*)(ws + alloc((size_t)N * 8 * 4));
  float* vsum   = (float*)(ws + alloc(128 * 4));
  int*   off    = (int*)(ws + alloc((size_t)(N + 1) * 4));
  int*   gcount = (int*)(ws + alloc((size_t)(NB + 1) * 4));
  int*   gbase  = (int*)(ws + alloc((size_t)(NB + 1) * 4));
  int*   gcursor= (int*)(ws + alloc((size_t)(NB + 1) * 4));
  unsigned int* staging = (unsigned int*)(ws + alloc((size_t)ET * 4));
  int*   csr    = (int*)(ws + alloc((size_t)ET * 4));
  unsigned short* W1t = (unsigned short*)(ws + alloc((size_t)128 * 128 * 2));
  float* va_s   = (float*)(ws + alloc(128 * 4));
  float* va_d   = (float*)(ws + alloc(128 * 4));

  // --- CSR build: bucketed counting sort ---
  hipMemsetAsync(gcount, 0, (size_t)NB * 4, stream);
  k_bhist<<<512, 256, 0, stream>>>(e_dst, gcount, E, N, NB);
  k_bscan<<<1, 512, 0, stream>>>(gcount, gbase, gcursor, NB, ET, off + N);
  constexpr int CHUNK = 8192;
  k_binpass<CHUNK><<<(ET + CHUNK - 1) / CHUNK, 256, 0, stream>>>(
      e_src, e_dst, gcursor, staging, E, N, NB);
  k_csrbuild<<<NB, 256, 0, stream>>>(gbase, staging, off, csr, N);

  // --- weights + layer-2 accumulator init ---
  k_prep_w<<<1, 256, 0, stream>>>(W1, W2, a2_src, a2_dst, W1t, va_s, va_d);
  hipMemsetAsync(Cv8, 0, (size_t)N * 8 * 4, stream);
  hipMemsetAsync(vsum, 0, 128 * 4, stream);

  const int gemm_grid = (N + 63) / 64;
  const int node_wave_grid = (N + 3) / 4;

  // --- layer 1: GEMM + fused alpha1; agg with fused alpha2 epilogue ---
  k_gemm1<<<gemm_grid, 256, 0, stream>>>(x, W1t, h1f, a1_src, a1_dst, as1, ad1, N);
  k_agg1<8><<<node_wave_grid, 256, 0, stream>>>(
      off, csr, as1, ad1, h1f, b1, va_s, va_d, g1b, as2, ad2, N);

  // --- layer 2 (algebraically collapsed through the mean) ---
  k_coef<<<node_wave_grid, 256, 0, stream>>>(off, csr, as2, ad2, Cv8, N);
  k_wsum<<<512, 256, 0, stream>>>(g1b, Cv8, vsum, N);
  k_finish<<<1, 64, 0, stream>>>(vsum, W2, b2, out, 1.0f / (float)N);
}

// Round 9
// 391.499 us; speedup vs baseline: 1.3443x; 1.3443x over previous
//
#include <hip/hip_runtime.h>
#include <cstdint>
#include <cstddef>

#define LEAKY_SLOPE 0.2f

typedef __attribute__((ext_vector_type(8))) short short8;   // 8 x bf16 frag
typedef __attribute__((ext_vector_type(4))) float f32x4;
typedef __attribute__((ext_vector_type(2))) float f32x2;

// ---- bf16 helpers (manual; RNE; inputs finite) ----
static __device__ inline unsigned short f2b(float f) {
  union { float f; unsigned int u; } c; c.f = f;
  unsigned int u = c.u;
  unsigned int r = (u + 0x7fffu + ((u >> 16) & 1u)) >> 16;
  return (unsigned short)r;
}
static __device__ inline float b2f(unsigned short b) {
  union { unsigned int u; float f; } c; c.u = ((unsigned int)b) << 16;
  return c.f;
}
// fp8 e4m3 (self-consistent encode/decode via HW cvt)
static __device__ inline unsigned char f2f8(float v) {
  int pk = __builtin_amdgcn_cvt_pk_fp8_f32(v, v, 0, false);
  return (unsigned char)(pk & 0xff);
}

// ================================================================ CSR build
__global__ __launch_bounds__(256) void k_bhist(const int* __restrict__ dst,
                                               int* __restrict__ gcount,
                                               int E, int N, int NB) {
  __shared__ int lh[512];
  for (int i = threadIdx.x; i < NB; i += 256) lh[i] = 0;
  __syncthreads();
  int stride = gridDim.x * blockDim.x;
  for (int idx = blockIdx.x * blockDim.x + threadIdx.x; idx < E + N; idx += stride) {
    int d = (idx < E) ? dst[idx] : (idx - E);   // self-loops at tail
    atomicAdd(&lh[d >> 8], 1);
  }
  __syncthreads();
  for (int i = threadIdx.x; i < NB; i += 256)
    if (lh[i]) atomicAdd(&gcount[i], lh[i]);
}

__global__ __launch_bounds__(512) void k_bscan(const int* __restrict__ gcount,
                                               int* __restrict__ gbase,
                                               int* __restrict__ gcursor,
                                               int NB, int ET, int* __restrict__ offN) {
  __shared__ int sm[512];
  int t = threadIdx.x;
  int v = (t < NB) ? gcount[t] : 0;
  sm[t] = v;
  __syncthreads();
  for (int o = 1; o < 512; o <<= 1) {
    int x = (t >= o) ? sm[t - o] : 0;
    __syncthreads();
    sm[t] += x;
    __syncthreads();
  }
  if (t < NB) {
    int b = sm[t] - v;
    gbase[t] = b;
    gcursor[t] = b;
  }
  if (t == 0) { gbase[NB] = ET; *offN = ET; }
}

template <int CHUNK>
__global__ __launch_bounds__(256) void k_binpass(const int* __restrict__ src,
                                                 const int* __restrict__ dst,
                                                 int* __restrict__ gcursor,
                                                 unsigned int* __restrict__ staging,
                                                 int E, int N, int NB) {
  __shared__ int lh[512];
  __shared__ int lbase[512];
  const int t = threadIdx.x;
  const int ET = E + N;
  const int e0 = blockIdx.x * CHUNK;
  const int e1 = min(e0 + CHUNK, ET);
  for (int i = t; i < NB; i += 256) lh[i] = 0;
  __syncthreads();
  for (int i = e0 + t; i < e1; i += 256) {
    int d = (i < E) ? dst[i] : (i - E);
    atomicAdd(&lh[d >> 8], 1);
  }
  __syncthreads();
  for (int i = t; i < NB; i += 256) {
    int c = lh[i];
    lbase[i] = c ? atomicAdd(&gcursor[i], c) : 0;
    lh[i] = 0;                       // reuse as local cursor
  }
  __syncthreads();
  for (int i = e0 + t; i < e1; i += 256) {
    int s, d;
    if (i < E) { s = src[i]; d = dst[i]; }
    else       { s = d = i - E; }
    int b = d >> 8;
    int r = atomicAdd(&lh[b], 1);
    staging[lbase[b] + r] = ((unsigned int)s << 8) | (unsigned int)(d & 255);
  }
}

__global__ __launch_bounds__(256) void k_csrbuild(const int* __restrict__ gbase,
                                                  const unsigned int* __restrict__ staging,
                                                  int* __restrict__ off,
                                                  int* __restrict__ csr,
                                                  int N) {
  __shared__ int sc[256];
  __shared__ int cur[256];
  const int b = blockIdx.x, t = threadIdx.x;
  const int s0 = gbase[b], s1 = gbase[b + 1];
  cur[t] = 0;
  __syncthreads();
  for (int i = s0 + t; i < s1; i += 256)
    atomicAdd(&cur[staging[i] & 255], 1);
  __syncthreads();
  int v = cur[t];
  sc[t] = v;
  __syncthreads();
  for (int o = 1; o < 256; o <<= 1) {
    int x = (t >= o) ? sc[t - o] : 0;
    __syncthreads();
    sc[t] += x;
    __syncthreads();
  }
  int excl = s0 + sc[t] - v;
  int node = b * 256 + t;
  if (node < N) off[node] = excl;
  __syncthreads();
  cur[t] = excl;
  __syncthreads();
  for (int i = s0 + t; i < s1; i += 256) {
    unsigned int pv = staging[i];
    int slot = atomicAdd(&cur[pv & 255], 1);
    csr[slot] = (int)(pv >> 8);
  }
}

// ---------------------------------------------------------------- weights prep
__global__ __launch_bounds__(256) void k_prep_w(const float* __restrict__ W1,
                                                const float* __restrict__ W2,
                                                unsigned short* __restrict__ W1t,
                                                unsigned short* __restrict__ W2t) {
  int t = threadIdx.x;
  for (int o = t; o < 128 * 128; o += 256) {
    int n = o >> 7, k = o & 127;
    W1t[o] = f2b(W1[k * 128 + n]);
  }
  for (int o = t; o < 64 * 128; o += 256) {
    int n = o >> 7, k = o & 127;
    W2t[o] = f2b(W2[k * 64 + n]);
  }
}

// ---------------------------------------------------------------- MFMA GEMM
// C[N][COLS] = A[N][128] @ B[128][COLS]; C stored fp8 e4m3 (gather payload).
// Fused alpha epilogue on the f32 accumulators (alpha stays full precision).
template <int COLS, bool SRC_F32>
__global__ __launch_bounds__(256) void k_gemm_bf16(const void* __restrict__ Ap,
                                                   const unsigned short* __restrict__ Bt,
                                                   unsigned char* __restrict__ C,
                                                   const float* __restrict__ av_src,
                                                   const float* __restrict__ av_dst,
                                                   float* __restrict__ as_,
                                                   float* __restrict__ ad_,
                                                   int N) {
  constexpr int K = 128;
  constexpr int LDA = K + 8;
  __shared__ __align__(16) unsigned short As[64 * LDA];
  __shared__ __align__(16) unsigned short Bs[COLS * LDA];
  const int t = threadIdx.x;
  const int wave = t >> 6, lane = t & 63;
  const int row0 = blockIdx.x * 64;

#pragma unroll
  for (int i = 0; i < 4; ++i) {
    int c = t + 256 * i;
    int r = c >> 4, cq = c & 15;
    int4 v = make_int4(0, 0, 0, 0);
    if (row0 + r < N) {
      if constexpr (SRC_F32) {
        const float* Ar = (const float*)Ap + (size_t)(row0 + r) * K + cq * 8;
        float4 u = *reinterpret_cast<const float4*>(Ar);
        float4 w = *reinterpret_cast<const float4*>(Ar + 4);
        v.x = (int)f2b(u.x) | ((int)f2b(u.y) << 16);
        v.y = (int)f2b(u.z) | ((int)f2b(u.w) << 16);
        v.z = (int)f2b(w.x) | ((int)f2b(w.y) << 16);
        v.w = (int)f2b(w.z) | ((int)f2b(w.w) << 16);
      } else {
        v = *reinterpret_cast<const int4*>((const unsigned short*)Ap +
                                           (size_t)(row0 + r) * K + cq * 8);
      }
    }
    *reinterpret_cast<int4*>(&As[r * LDA + cq * 8]) = v;
  }
#pragma unroll
  for (int i = 0; i < COLS / 16; ++i) {
    int c = t + 256 * i;
    int r = c >> 4, cq = c & 15;
    *reinterpret_cast<int4*>(&Bs[r * LDA + cq * 8]) =
        *reinterpret_cast<const int4*>(Bt + (size_t)r * K + cq * 8);
  }
  __syncthreads();

  const int m15 = lane & 15;
  const int koff = (lane >> 4) * 8;
  const int arow = wave * 16 + m15;

  f32x4 acc[COLS / 16];
#pragma unroll
  for (int ct = 0; ct < COLS / 16; ++ct) acc[ct] = (f32x4){0.f, 0.f, 0.f, 0.f};

#pragma unroll
  for (int kk = 0; kk < K / 32; ++kk) {
    short8 af = *reinterpret_cast<const short8*>(&As[arow * LDA + kk * 32 + koff]);
#pragma unroll
    for (int ct = 0; ct < COLS / 16; ++ct) {
      short8 bf = *reinterpret_cast<const short8*>(&Bs[(ct * 16 + m15) * LDA + kk * 32 + koff]);
      acc[ct] = __builtin_amdgcn_mfma_f32_16x16x32_bf16(af, bf, acc[ct], 0, 0, 0);
    }
  }

  // C store (fp8 bytes)
#pragma unroll
  for (int ct = 0; ct < COLS / 16; ++ct) {
#pragma unroll
    for (int r = 0; r < 4; ++r) {
      int grow = row0 + wave * 16 + (lane >> 4) * 4 + r;
      if (grow < N)
        C[(size_t)grow * COLS + ct * 16 + m15] = f2f8(acc[ct][r]);
    }
  }

  // fused alpha epilogue (f32-accurate)
  {
    float ps[4] = {0.f, 0.f, 0.f, 0.f}, pd[4] = {0.f, 0.f, 0.f, 0.f};
#pragma unroll
    for (int ct = 0; ct < COLS / 16; ++ct) {
      float av = av_src[ct * 16 + m15];
      float bv = av_dst[ct * 16 + m15];
#pragma unroll
      for (int r = 0; r < 4; ++r) {
        ps[r] += acc[ct][r] * av;
        pd[r] += acc[ct][r] * bv;
      }
    }
#pragma unroll
    for (int o = 1; o < 16; o <<= 1) {
#pragma unroll
      for (int r = 0; r < 4; ++r) {
        ps[r] += __shfl_xor(ps[r], o);
        pd[r] += __shfl_xor(pd[r], o);
      }
    }
    if (m15 == 0) {
#pragma unroll
      for (int r = 0; r < 4; ++r) {
        int grow = row0 + wave * 16 + (lane >> 4) * 4 + r;
        if (grow < N) { as_[grow] = ps[r]; ad_[grow] = pd[r]; }
      }
    }
  }
}

// ---------------------------------------------------------------- layer-1 aggregation
// One wave per dst node, single pass over fp8 h1 (F=128):
//   g1 = relu((sum_j exp(e_j) h[src_j]) / sum_j exp(e_j) + b1), stored bf16.
template <int DEPTH>
__global__ __launch_bounds__(256) void k_agg1(const int* __restrict__ off,
                                              const int* __restrict__ csr,
                                              const float* __restrict__ as_,
                                              const float* __restrict__ ad_,
                                              const unsigned char* __restrict__ h,
                                              const float* __restrict__ bias,
                                              unsigned short* __restrict__ g1,
                                              int N) {
  constexpr int F = 128, LPR = 16, GPI = 4;   // lanes/row, rows per wave-load
  int wid = (blockIdx.x * blockDim.x + threadIdx.x) >> 6;
  int lane = threadIdx.x & 63;
  if (wid >= N) return;
  const int s0 = off[wid], s1 = off[wid + 1];
  const float adv = ad_[wid];
  const int g  = lane / LPR;
  const int fl = lane % LPR;
  const unsigned char* hb = h + (size_t)fl * 8;

  f32x2 acc2[4] = {{0.f, 0.f}, {0.f, 0.f}, {0.f, 0.f}, {0.f, 0.f}};
  float lsum = 0.f;

  for (int base = s0; base < s1; base += 64) {
    int i = base + lane;
    int sv = 0;
    float wexp = 0.f;
    if (i < s1) {
      sv = csr[i];
      float e = as_[sv] + adv;
      e = (e > 0.f) ? e : LEAKY_SLOPE * e;
      wexp = __expf(e);
      lsum += wexp;
    }
    const int jn = min(64, s1 - base);
    int jj = 0;
    for (; jj + DEPTH * GPI <= jn; jj += DEPTH * GPI) {
      int sj[DEPTH];
      float wv[DEPTH];
      uint2 u[DEPTH];
#pragma unroll
      for (int k = 0; k < DEPTH; ++k) {
        sj[k] = __shfl(sv, jj + g + k * GPI);
        wv[k] = __shfl(wexp, jj + g + k * GPI);
      }
#pragma unroll
      for (int k = 0; k < DEPTH; ++k)
        u[k] = *reinterpret_cast<const uint2*>(hb + (size_t)sj[k] * F);
#pragma unroll
      for (int k = 0; k < DEPTH; ++k) {
        f32x2 w2 = {wv[k], wv[k]};
        acc2[0] += w2 * __builtin_amdgcn_cvt_pk_f32_fp8(u[k].x, false);
        acc2[1] += w2 * __builtin_amdgcn_cvt_pk_f32_fp8(u[k].x, true);
        acc2[2] += w2 * __builtin_amdgcn_cvt_pk_f32_fp8(u[k].y, false);
        acc2[3] += w2 * __builtin_amdgcn_cvt_pk_f32_fp8(u[k].y, true);
      }
    }
    for (; jj < jn; jj += GPI) {
      int sj0 = __shfl(sv, jj + g);        // <= 63 always; zero-weight slack ok
      float w0 = __shfl(wexp, jj + g);
      uint2 u0 = *reinterpret_cast<const uint2*>(hb + (size_t)sj0 * F);
      f32x2 w2 = {w0, w0};
      acc2[0] += w2 * __builtin_amdgcn_cvt_pk_f32_fp8(u0.x, false);
      acc2[1] += w2 * __builtin_amdgcn_cvt_pk_f32_fp8(u0.x, true);
      acc2[2] += w2 * __builtin_amdgcn_cvt_pk_f32_fp8(u0.y, false);
      acc2[3] += w2 * __builtin_amdgcn_cvt_pk_f32_fp8(u0.y, true);
    }
  }

  for (int o = 32; o; o >>= 1) lsum += __shfl_xor(lsum, o);
  const float inv_s = 1.f / (lsum + 1e-16f);

#pragma unroll
  for (int o = LPR; o < 64; o <<= 1) {
#pragma unroll
    for (int k = 0; k < 4; ++k) {
      acc2[k][0] += __shfl_xor(acc2[k][0], o);
      acc2[k][1] += __shfl_xor(acc2[k][1], o);
    }
  }

  if (g == 0) {
    float ov[8];
#pragma unroll
    for (int k = 0; k < 8; ++k)
      ov[k] = fmaxf(acc2[k >> 1][k & 1] * inv_s + bias[fl * 8 + k], 0.f);
    int4 pk;
    pk.x = (int)f2b(ov[0]) | ((int)f2b(ov[1]) << 16);
    pk.y = (int)f2b(ov[2]) | ((int)f2b(ov[3]) << 16);
    pk.z = (int)f2b(ov[4]) | ((int)f2b(ov[5]) << 16);
    pk.w = (int)f2b(ov[6]) | ((int)f2b(ov[7]) << 16);
    *reinterpret_cast<int4*>(g1 + (size_t)wid * F + fl * 8) = pk;
  }
}

// ---------------------------------------------------------------- layer-2 aggregation + mean (fused)
// Grid-stride waves over dst nodes; per node: softmax-weighted fp8 h2 gather
// (F=64); mean accumulated in registers (deferred cross-group reduction),
// block-reduced in LDS, ~64 atomics per block into vsum.
template <int DEPTH>
__global__ __launch_bounds__(256) void k_agg2m(const int* __restrict__ off,
                                               const int* __restrict__ csr,
                                               const float* __restrict__ as_,
                                               const float* __restrict__ ad_,
                                               const unsigned char* __restrict__ h,
                                               float* __restrict__ vsum,
                                               int N, float invN) {
  constexpr int F = 64, LPR = 8, GPI = 8;
  const int lane = threadIdx.x & 63;
  const int wv = (blockIdx.x * blockDim.x + threadIdx.x) >> 6;
  const int nw = (gridDim.x * blockDim.x) >> 6;
  const int g  = lane >> 3;
  const int fl = lane & 7;
  const unsigned char* hb = h + (size_t)fl * 8;

  f32x2 macc[4] = {{0.f, 0.f}, {0.f, 0.f}, {0.f, 0.f}, {0.f, 0.f}};

  for (int wid = wv; wid < N; wid += nw) {
    const int s0 = off[wid], s1 = off[wid + 1];
    const float adv = ad_[wid];
    f32x2 acc2[4] = {{0.f, 0.f}, {0.f, 0.f}, {0.f, 0.f}, {0.f, 0.f}};
    float lsum = 0.f;

    for (int base = s0; base < s1; base += 64) {
      int i = base + lane;
      int sv = 0;
      float wexp = 0.f;
      if (i < s1) {
        sv = csr[i];
        float e = as_[sv] + adv;
        e = (e > 0.f) ? e : LEAKY_SLOPE * e;
        wexp = __expf(e);
        lsum += wexp;
      }
      const int jn = min(64, s1 - base);
      int jj = 0;
      for (; jj + DEPTH * GPI <= jn; jj += DEPTH * GPI) {
        int sj[DEPTH];
        float wvv[DEPTH];
        uint2 u[DEPTH];
#pragma unroll
        for (int k = 0; k < DEPTH; ++k) {
          sj[k] = __shfl(sv, jj + g + k * GPI);
          wvv[k] = __shfl(wexp, jj + g + k * GPI);
        }
#pragma unroll
        for (int k = 0; k < DEPTH; ++k)
          u[k] = *reinterpret_cast<const uint2*>(hb + (size_t)sj[k] * F);
#pragma unroll
        for (int k = 0; k < DEPTH; ++k) {
          f32x2 w2 = {wvv[k], wvv[k]};
          acc2[0] += w2 * __builtin_amdgcn_cvt_pk_f32_fp8(u[k].x, false);
          acc2[1] += w2 * __builtin_amdgcn_cvt_pk_f32_fp8(u[k].x, true);
          acc2[2] += w2 * __builtin_amdgcn_cvt_pk_f32_fp8(u[k].y, false);
          acc2[3] += w2 * __builtin_amdgcn_cvt_pk_f32_fp8(u[k].y, true);
        }
      }
      for (; jj < jn; jj += GPI) {
        int sj0 = __shfl(sv, jj + g);      // <= 63; zero-weight slack ok
        float w0 = __shfl(wexp, jj + g);
        uint2 u0 = *reinterpret_cast<const uint2*>(hb + (size_t)sj0 * F);
        f32x2 w2 = {w0, w0};
        acc2[0] += w2 * __builtin_amdgcn_cvt_pk_f32_fp8(u0.x, false);
        acc2[1] += w2 * __builtin_amdgcn_cvt_pk_f32_fp8(u0.x, true);
        acc2[2] += w2 * __builtin_amdgcn_cvt_pk_f32_fp8(u0.y, false);
        acc2[3] += w2 * __builtin_amdgcn_cvt_pk_f32_fp8(u0.y, true);
      }
    }

    for (int o = 32; o; o >>= 1) lsum += __shfl_xor(lsum, o);
    f32x2 inv_s = {1.f / (lsum + 1e-16f), 1.f / (lsum + 1e-16f)};
#pragma unroll
    for (int k = 0; k < 4; ++k) macc[k] += inv_s * acc2[k];
  }

  // cross-group reduction (sum over g): offsets 8,16,32
#pragma unroll
  for (int o = LPR; o < 64; o <<= 1) {
#pragma unroll
    for (int k = 0; k < 4; ++k) {
      macc[k][0] += __shfl_xor(macc[k][0], o);
      macc[k][1] += __shfl_xor(macc[k][1], o);
    }
  }

  __shared__ float sm[4 * 64];
  const int wloc = threadIdx.x >> 6;
  if (g == 0) {
#pragma unroll
    for (int k = 0; k < 4; ++k) {
      sm[wloc * 64 + fl * 8 + 2 * k]     = macc[k][0];
      sm[wloc * 64 + fl * 8 + 2 * k + 1] = macc[k][1];
    }
  }
  __syncthreads();
  if (threadIdx.x < 64) {
    float s = sm[threadIdx.x] + sm[64 + threadIdx.x] +
              sm[128 + threadIdx.x] + sm[192 + threadIdx.x];
    atomicAdd(&vsum[threadIdx.x], s * invN);
  }
}

// ---------------------------------------------------------------- finish
__global__ __launch_bounds__(64) void k_finish(const float* __restrict__ v,
                                               const float* __restrict__ b2,
                                               float* __restrict__ out) {
  int c = threadIdx.x;
  out[c] = v[c] + b2[c];
}

// ---------------------------------------------------------------- launch
extern "C" void kernel_launch(void* const* d_in, const int* in_sizes, int n_in,
                              void* d_out, int out_size, void* d_ws, size_t ws_size,
                              hipStream_t stream) {
  (void)n_in; (void)out_size; (void)ws_size;
  const float* x      = (const float*)d_in[0];
  const int*   edges  = (const int*)d_in[1];
  const float* W1     = (const float*)d_in[2];
  const float* a1_src = (const float*)d_in[3];
  const float* a1_dst = (const float*)d_in[4];
  const float* b1     = (const float*)d_in[5];
  const float* W2     = (const float*)d_in[6];
  const float* a2_src = (const float*)d_in[7];
  const float* a2_dst = (const float*)d_in[8];
  const float* b2     = (const float*)d_in[9];
  float* out = (float*)d_out;

  const int N = in_sizes[0] / 128;     // 100000
  const int E = in_sizes[1] / 2;       // 3200000
  const int ET = E + N;
  const int NB = (N + 255) >> 8;       // 391 buckets of 256 nodes

  const int* e_src = edges;
  const int* e_dst = edges + E;

  char* ws = (char*)d_ws;
  size_t o = 0;
  auto alloc = [&](size_t bytes) {
    size_t p = o;
    o += (bytes + 511) & ~(size_t)511;
    return p;
  };
  unsigned char*  h1f = (unsigned char*)(ws + alloc((size_t)N * 128));
  unsigned short* g1b = (unsigned short*)(ws + alloc((size_t)N * 128 * 2));
  unsigned char*  h2f = (unsigned char*)(ws + alloc((size_t)N * 64));
  float* as1    = (float*)(ws + alloc((size_t)N * 4));
  float* ad1    = (float*)(ws + alloc((size_t)N * 4));
  float* as2    = (float*)(ws + alloc((size_t)N * 4));
  float* ad2    = (float*)(ws + alloc((size_t)N * 4));
  float* vsum   = (float*)(ws + alloc(64 * 4));
  int*   off    = (int*)(ws + alloc((size_t)(N + 1) * 4));
  int*   gcount = (int*)(ws + alloc((size_t)(NB + 1) * 4));
  int*   gbase  = (int*)(ws + alloc((size_t)(NB + 1) * 4));
  int*   gcursor= (int*)(ws + alloc((size_t)(NB + 1) * 4));
  unsigned int* staging = (unsigned int*)(ws + alloc((size_t)ET * 4));
  int*   csr    = (int*)(ws + alloc((size_t)ET * 4));
  unsigned short* W1t = (unsigned short*)(ws + alloc((size_t)128 * 128 * 2));
  unsigned short* W2t = (unsigned short*)(ws + alloc((size_t)64 * 128 * 2));

  // --- CSR build: bucketed counting sort ---
  hipMemsetAsync(gcount, 0, (size_t)NB * 4, stream);
  k_bhist<<<512, 256, 0, stream>>>(e_dst, gcount, E, N, NB);
  k_bscan<<<1, 512, 0, stream>>>(gcount, gbase, gcursor, NB, ET, off + N);
  constexpr int CHUNK = 8192;
  k_binpass<CHUNK><<<(ET + CHUNK - 1) / CHUNK, 256, 0, stream>>>(
      e_src, e_dst, gcursor, staging, E, N, NB);
  k_csrbuild<<<NB, 256, 0, stream>>>(gbase, staging, off, csr, N);

  // --- weights + mean accumulator init ---
  k_prep_w<<<1, 256, 0, stream>>>(W1, W2, W1t, W2t);
  hipMemsetAsync(vsum, 0, 64 * 4, stream);

  const int gemm_grid = (N + 63) / 64;
  const int node_wave_grid = (N + 3) / 4;

  // --- layer 1: GEMM (+fused alpha1) -> fp8 h1; agg -> bf16 g1 ---
  k_gemm_bf16<128, true><<<gemm_grid, 256, 0, stream>>>(
      x, W1t, h1f, a1_src, a1_dst, as1, ad1, N);
  k_agg1<8><<<node_wave_grid, 256, 0, stream>>>(
      off, csr, as1, ad1, h1f, b1, g1b, N);

  // --- layer 2: GEMM (+fused alpha2) -> fp8 h2; agg with fused mean ---
  k_gemm_bf16<64, false><<<gemm_grid, 256, 0, stream>>>(
      g1b, W2t, h2f, a2_src, a2_dst, as2, ad2, N);
  k_agg2m<4><<<1024, 256, 0, stream>>>(off, csr, as2, ad2, h2f, vsum, N,
                                       1.0f / (float)N);
  k_finish<<<1, 64, 0, stream>>>(vsum, b2, out);
}